// Round 1
// baseline (891.456 us; speedup 1.0000x reference)
//
#include <hip/hip_runtime.h>

#define NFEAT 128
#define EPSV 1e-5f

// ---------------- column stats (mean/var over N rows, 128 cols) ----------------
__global__ __launch_bounds__(256) void k_stats(const float* __restrict__ X,
    float* __restrict__ sum, float* __restrict__ sumsq, long total)
{
    float s = 0.f, q = 0.f;
    long stride = (long)gridDim.x * blockDim.x;
    for (long i = (long)blockIdx.x * blockDim.x + threadIdx.x; i < total; i += stride) {
        float v = X[i];
        s += v;
        q = fmaf(v, v, q);
    }
    __shared__ float ls[256], lq[256];
    ls[threadIdx.x] = s; lq[threadIdx.x] = q;
    __syncthreads();
    if (threadIdx.x < 128) {
        int c = threadIdx.x;            // stride is a multiple of 128 -> col == tid&127
        s = ls[c] + ls[c + 128];
        q = lq[c] + lq[c + 128];
        unsafeAtomicAdd(&sum[c], s);
        unsafeAtomicAdd(&sumsq[c], q);
    }
}

// ---------------- BN apply: xn = (x-mu)*rstd*gamma + beta ----------------
__global__ __launch_bounds__(256) void k_bn(const float* __restrict__ X,
    const float* __restrict__ sum, const float* __restrict__ sumsq,
    const float* __restrict__ gamma, const float* __restrict__ beta,
    float* __restrict__ XN, long total4, float invN)
{
    __shared__ float sc[NFEAT], sh[NFEAT];
    if (threadIdx.x < NFEAT) {
        int c = threadIdx.x;
        float mu = sum[c] * invN;
        float var = fmaf(-mu, mu, sumsq[c] * invN);
        float r = rsqrtf(var + EPSV);
        float g = r * gamma[c];
        sc[c] = g;
        sh[c] = fmaf(-mu, g, beta[c]);
    }
    __syncthreads();
    const float4* X4 = (const float4*)X;
    float4* XN4 = (float4*)XN;
    long stride = (long)gridDim.x * blockDim.x;
    for (long i = (long)blockIdx.x * blockDim.x + threadIdx.x; i < total4; i += stride) {
        int c0 = (int)((i << 2) & (NFEAT - 1));
        float4 v = X4[i];
        float4 o;
        o.x = fmaf(v.x, sc[c0 + 0], sh[c0 + 0]);
        o.y = fmaf(v.y, sc[c0 + 1], sh[c0 + 1]);
        o.z = fmaf(v.z, sc[c0 + 2], sh[c0 + 2]);
        o.w = fmaf(v.w, sc[c0 + 3], sh[c0 + 3]);
        XN4[i] = o;
    }
}

// ---------------- degree histogram over dst ----------------
__global__ __launch_bounds__(256) void k_deg(const int* __restrict__ dst,
    int* __restrict__ deg, int E)
{
    int stride = gridDim.x * blockDim.x;
    for (int e = blockIdx.x * blockDim.x + threadIdx.x; e < E; e += stride)
        atomicAdd(&deg[dst[e]], 1);
}

// ---------------- single-block exclusive scan -> row_ptr, nxt ----------------
__global__ __launch_bounds__(1024) void k_scan(const int* __restrict__ deg,
    int* __restrict__ rp, int* __restrict__ nxt, int N)
{
    __shared__ int ps[1024];
    int t = threadIdx.x;
    int chunk = (N + 1023) >> 10;
    int lo = t * chunk; if (lo > N) lo = N;
    int hi = lo + chunk; if (hi > N) hi = N;
    int s = 0;
    for (int i = lo; i < hi; ++i) s += deg[i];
    ps[t] = s;
    __syncthreads();
    for (int off = 1; off < 1024; off <<= 1) {
        int v = ps[t];
        if (t >= off) v += ps[t - off];
        __syncthreads();
        ps[t] = v;
        __syncthreads();
    }
    int base = (t == 0) ? 0 : ps[t - 1];
    for (int i = lo; i < hi; ++i) {
        rp[i] = base; nxt[i] = base; base += deg[i];
    }
    if (t == 1023) rp[N] = base;
}

// ---------------- dinv = rsqrt(deg+1)  (self-loop) ----------------
__global__ __launch_bounds__(256) void k_dinv(const int* __restrict__ deg,
    float* __restrict__ dinv, int N)
{
    int i = blockIdx.x * 256 + threadIdx.x;
    if (i < N) dinv[i] = rsqrtf((float)(deg[i] + 1));
}

// ---------------- CSR fill: bucket src by dst ----------------
__global__ __launch_bounds__(256) void k_fill(const int* __restrict__ src,
    const int* __restrict__ dst, int* __restrict__ nxt, int* __restrict__ csr, int E)
{
    int stride = gridDim.x * blockDim.x;
    for (int e = blockIdx.x * blockDim.x + threadIdx.x; e < E; e += stride) {
        int p = atomicAdd(&nxt[dst[e]], 1);
        csr[p] = src[e];
    }
}

// ---------------- GEMM: Y[n][o] = dinv[n] * sum_k X[n][k]*W[o][k] ----------------
// LDS: wt (transposed W, 64KB) + xs (32-row tile, 16KB) = 80KB -> 2 blocks/CU
__global__ __launch_bounds__(256) void k_gemm128(const float* __restrict__ X,
    const float* __restrict__ W, const float* __restrict__ dinv,
    float* __restrict__ Y, int N)
{
    __shared__ float wt[NFEAT][NFEAT];   // wt[k][o] = W[o][k]
    __shared__ float xs[32][NFEAT];      // xs[r][k]
    for (int idx = threadIdx.x; idx < NFEAT * NFEAT; idx += 256) {
        int o = idx >> 7, k = idx & 127;
        wt[k][o] = W[idx];
    }
    int tx = threadIdx.x & 31;   // 4 cols: 4*tx .. 4*tx+3
    int ty = threadIdx.x >> 5;   // 4 rows: 4*ty .. 4*ty+3
    int ntiles = N >> 5;
    for (int tile = blockIdx.x; tile < ntiles; tile += gridDim.x) {
        int row0 = tile << 5;
        __syncthreads();   // also covers initial wt writes on first iter
        #pragma unroll
        for (int it = 0; it < 16; ++it) {
            int idx = it * 256 + threadIdx.x;
            int r = idx >> 7, k = idx & 127;
            xs[r][k] = X[(long)(row0 + r) * NFEAT + k];
        }
        __syncthreads();
        float acc[4][4];
        #pragma unroll
        for (int i = 0; i < 4; ++i)
            #pragma unroll
            for (int j = 0; j < 4; ++j) acc[i][j] = 0.f;
        #pragma unroll 4
        for (int k = 0; k < NFEAT; ++k) {
            float4 b = *(const float4*)&wt[k][tx * 4];
            float a0 = xs[ty * 4 + 0][k];
            float a1 = xs[ty * 4 + 1][k];
            float a2 = xs[ty * 4 + 2][k];
            float a3 = xs[ty * 4 + 3][k];
            acc[0][0] = fmaf(a0, b.x, acc[0][0]); acc[0][1] = fmaf(a0, b.y, acc[0][1]);
            acc[0][2] = fmaf(a0, b.z, acc[0][2]); acc[0][3] = fmaf(a0, b.w, acc[0][3]);
            acc[1][0] = fmaf(a1, b.x, acc[1][0]); acc[1][1] = fmaf(a1, b.y, acc[1][1]);
            acc[1][2] = fmaf(a1, b.z, acc[1][2]); acc[1][3] = fmaf(a1, b.w, acc[1][3]);
            acc[2][0] = fmaf(a2, b.x, acc[2][0]); acc[2][1] = fmaf(a2, b.y, acc[2][1]);
            acc[2][2] = fmaf(a2, b.z, acc[2][2]); acc[2][3] = fmaf(a2, b.w, acc[2][3]);
            acc[3][0] = fmaf(a3, b.x, acc[3][0]); acc[3][1] = fmaf(a3, b.y, acc[3][1]);
            acc[3][2] = fmaf(a3, b.z, acc[3][2]); acc[3][3] = fmaf(a3, b.w, acc[3][3]);
        }
        #pragma unroll
        for (int i = 0; i < 4; ++i) {
            int r = row0 + ty * 4 + i;
            float dv = dinv[r];
            float4 o = make_float4(acc[i][0] * dv, acc[i][1] * dv,
                                   acc[i][2] * dv, acc[i][3] * dv);
            *(float4*)&Y[(long)r * NFEAT + tx * 4] = o;
        }
    }
}

// ---------------- aggregation: out[v] = relu(dinv[v]*(tt[v] + sum_in tt[u]) + b) ----
// one wave per dst node, 2 cols (float2) per lane
__global__ __launch_bounds__(256) void k_agg(const float2* __restrict__ TT,
    const int* __restrict__ rp, const int* __restrict__ csr,
    const float* __restrict__ dinv, const float* __restrict__ bias,
    float2* __restrict__ OUT, int N)
{
    int wid = (blockIdx.x * 256 + threadIdx.x) >> 6;
    if (wid >= N) return;
    int lane = threadIdx.x & 63;
    long base = (long)wid * 64;
    float2 acc = TT[base + lane];   // self-loop term
    int e = rp[wid], e1 = rp[wid + 1];
    for (; e + 4 <= e1; e += 4) {
        int s0 = csr[e], s1 = csr[e + 1], s2 = csr[e + 2], s3 = csr[e + 3];
        float2 m0 = TT[(long)s0 * 64 + lane];
        float2 m1 = TT[(long)s1 * 64 + lane];
        float2 m2 = TT[(long)s2 * 64 + lane];
        float2 m3 = TT[(long)s3 * 64 + lane];
        acc.x += (m0.x + m1.x) + (m2.x + m3.x);
        acc.y += (m0.y + m1.y) + (m2.y + m3.y);
    }
    for (; e < e1; ++e) {
        int s = csr[e];
        float2 m = TT[(long)s * 64 + lane];
        acc.x += m.x; acc.y += m.y;
    }
    float dv = dinv[wid];
    float2 o;
    o.x = fmaxf(fmaf(acc.x, dv, bias[lane * 2 + 0]), 0.f);
    o.y = fmaxf(fmaf(acc.y, dv, bias[lane * 2 + 1]), 0.f);
    OUT[base + lane] = o;
}

// ---------------- fused head: relu(H@Wc1^T + bc1) @ Wc2^T + bc2 ----------------
__global__ __launch_bounds__(256) void k_head(const float* __restrict__ H,
    const float* __restrict__ Wc1, const float* __restrict__ bc1,
    const float* __restrict__ Wc2, const float* __restrict__ bc2,
    float* __restrict__ OUT, int N)
{
    __shared__ float w1[16][132];
    __shared__ float hs[16][132];
    __shared__ float h16[16][17];
    for (int idx = threadIdx.x; idx < 16 * NFEAT; idx += 256) {
        int o = idx >> 7, k = idx & 127;
        w1[o][k] = Wc1[idx];
    }
    int ntiles = (N + 15) >> 4;
    for (int tile = blockIdx.x; tile < ntiles; tile += gridDim.x) {
        int row0 = tile << 4;
        __syncthreads();   // also covers w1 init on first iter
        #pragma unroll
        for (int it = 0; it < 8; ++it) {
            int idx = it * 256 + threadIdx.x;
            int r = idx >> 7, k = idx & 127;
            int row = row0 + r;
            hs[r][k] = (row < N) ? H[(long)row * NFEAT + k] : 0.f;
        }
        __syncthreads();
        int r = threadIdx.x >> 4, o = threadIdx.x & 15;
        float acc = 0.f;
        #pragma unroll 8
        for (int k = 0; k < NFEAT; ++k) acc = fmaf(hs[r][k], w1[o][k], acc);
        h16[r][o] = fmaxf(acc + bc1[o], 0.f);
        __syncthreads();
        if (threadIdx.x < 32) {
            int rr = threadIdx.x >> 1, j = threadIdx.x & 1;
            float a = bc2[j];
            #pragma unroll
            for (int o2 = 0; o2 < 16; ++o2) a = fmaf(h16[rr][o2], Wc2[j * 16 + o2], a);
            int row = row0 + rr;
            if (row < N) OUT[(long)row * 2 + j] = a;
        }
        __syncthreads();
    }
}

extern "C" void kernel_launch(void* const* d_in, const int* in_sizes, int n_in,
                              void* d_out, int out_size, void* d_ws, size_t ws_size,
                              hipStream_t stream) {
    const float* x     = (const float*)d_in[0];
    const int*   ei    = (const int*)d_in[1];
    const float* gamma = (const float*)d_in[2];
    const float* beta  = (const float*)d_in[3];
    const float* W1    = (const float*)d_in[4];
    const float* b1    = (const float*)d_in[5];
    const float* W2    = (const float*)d_in[6];
    const float* b2    = (const float*)d_in[7];
    const float* Wc1   = (const float*)d_in[8];
    const float* bc1   = (const float*)d_in[9];
    const float* Wc2   = (const float*)d_in[10];
    const float* bc2   = (const float*)d_in[11];

    int N = in_sizes[0] / NFEAT;
    int E = in_sizes[1] / 2;
    const int* srcI = ei;
    const int* dstI = ei + E;

    char* ws = (char*)d_ws;
    size_t off = 0;
    auto alloc = [&](size_t bytes) {
        void* p = ws + off;
        off += bytes;
        off = (off + 511) & ~(size_t)511;
        return p;
    };
    float* buf0  = (float*)alloc((size_t)N * NFEAT * 4);
    float* buf1  = (float*)alloc((size_t)N * NFEAT * 4);
    float* sum   = (float*)alloc(NFEAT * 4);
    float* sumsq = (float*)alloc(NFEAT * 4);
    int*   deg   = (int*)alloc((size_t)N * 4);
    int*   rp    = (int*)alloc((size_t)(N + 1) * 4);
    int*   nxt   = (int*)alloc((size_t)N * 4);
    float* dinv  = (float*)alloc((size_t)N * 4);
    int*   csr   = (int*)alloc((size_t)E * 4);
    (void)ws_size;

    hipMemsetAsync(sum, 0, NFEAT * 4, stream);
    hipMemsetAsync(sumsq, 0, NFEAT * 4, stream);
    hipMemsetAsync(deg, 0, (size_t)N * 4, stream);

    long total = (long)N * NFEAT;
    k_stats<<<1024, 256, 0, stream>>>(x, sum, sumsq, total);
    k_bn<<<2048, 256, 0, stream>>>(x, sum, sumsq, gamma, beta, buf0, total >> 2, 1.0f / (float)N);
    k_deg<<<1024, 256, 0, stream>>>(dstI, deg, E);
    k_scan<<<1, 1024, 0, stream>>>(deg, rp, nxt, N);
    k_dinv<<<(N + 255) / 256, 256, 0, stream>>>(deg, dinv, N);
    k_fill<<<1024, 256, 0, stream>>>(srcI, dstI, nxt, csr, E);

    // layer 1
    k_gemm128<<<1024, 256, 0, stream>>>(buf0, W1, dinv, buf1, N);
    k_agg<<<(N + 3) / 4, 256, 0, stream>>>((const float2*)buf1, rp, csr, dinv, b1, (float2*)buf0, N);
    // layer 2
    k_gemm128<<<1024, 256, 0, stream>>>(buf0, W2, dinv, buf1, N);
    k_agg<<<(N + 3) / 4, 256, 0, stream>>>((const float2*)buf1, rp, csr, dinv, b2, (float2*)buf0, N);
    // head
    k_head<<<2048, 256, 0, stream>>>(buf0, Wc1, bc1, Wc2, bc2, (float*)d_out, N);
}

// Round 2
// 689.921 us; speedup vs baseline: 1.2921x; 1.2921x over previous
//
#include <hip/hip_runtime.h>

#define NFEAT 128
#define EPSV 1e-5f

// ---------------- column stats (mean/var over N rows, 128 cols) ----------------
__global__ __launch_bounds__(256) void k_stats(const float* __restrict__ X,
    float* __restrict__ sum, float* __restrict__ sumsq, long total)
{
    float s = 0.f, q = 0.f;
    long stride = (long)gridDim.x * blockDim.x;
    for (long i = (long)blockIdx.x * blockDim.x + threadIdx.x; i < total; i += stride) {
        float v = X[i];
        s += v;
        q = fmaf(v, v, q);
    }
    __shared__ float ls[256], lq[256];
    ls[threadIdx.x] = s; lq[threadIdx.x] = q;
    __syncthreads();
    if (threadIdx.x < 128) {
        int c = threadIdx.x;            // stride is a multiple of 128 -> col == tid&127
        s = ls[c] + ls[c + 128];
        q = lq[c] + lq[c + 128];
        unsafeAtomicAdd(&sum[c], s);
        unsafeAtomicAdd(&sumsq[c], q);
    }
}

// ---------------- BN apply: xn = (x-mu)*rstd*gamma + beta ----------------
__global__ __launch_bounds__(256) void k_bn(const float* __restrict__ X,
    const float* __restrict__ sum, const float* __restrict__ sumsq,
    const float* __restrict__ gamma, const float* __restrict__ beta,
    float* __restrict__ XN, long total4, float invN)
{
    __shared__ float sc[NFEAT], sh[NFEAT];
    if (threadIdx.x < NFEAT) {
        int c = threadIdx.x;
        float mu = sum[c] * invN;
        float var = fmaf(-mu, mu, sumsq[c] * invN);
        float r = rsqrtf(var + EPSV);
        float g = r * gamma[c];
        sc[c] = g;
        sh[c] = fmaf(-mu, g, beta[c]);
    }
    __syncthreads();
    const float4* X4 = (const float4*)X;
    float4* XN4 = (float4*)XN;
    long stride = (long)gridDim.x * blockDim.x;
    for (long i = (long)blockIdx.x * blockDim.x + threadIdx.x; i < total4; i += stride) {
        int c0 = (int)((i << 2) & (NFEAT - 1));
        float4 v = X4[i];
        float4 o;
        o.x = fmaf(v.x, sc[c0 + 0], sh[c0 + 0]);
        o.y = fmaf(v.y, sc[c0 + 1], sh[c0 + 1]);
        o.z = fmaf(v.z, sc[c0 + 2], sh[c0 + 2]);
        o.w = fmaf(v.w, sc[c0 + 3], sh[c0 + 3]);
        XN4[i] = o;
    }
}

// ---------------- degree histogram over dst ----------------
__global__ __launch_bounds__(256) void k_deg(const int* __restrict__ dst,
    int* __restrict__ deg, int E)
{
    int stride = gridDim.x * blockDim.x;
    for (int e = blockIdx.x * blockDim.x + threadIdx.x; e < E; e += stride)
        atomicAdd(&deg[dst[e]], 1);
}

// ---------------- 3-phase device-wide exclusive scan ----------------
// phase A: per-block (1024 elems) sum -> part[b]
__global__ __launch_bounds__(256) void k_scan_a(const int* __restrict__ deg,
    int* __restrict__ part, int N)
{
    int base = blockIdx.x << 10;
    int t = threadIdx.x;
    int s = 0;
    #pragma unroll
    for (int j = 0; j < 4; ++j) {
        int i = base + t * 4 + j;
        if (i < N) s += deg[i];
    }
    __shared__ int ls[256];
    ls[t] = s;
    __syncthreads();
    #pragma unroll
    for (int off = 128; off > 0; off >>= 1) {
        if (t < off) ls[t] += ls[t + off];
        __syncthreads();
    }
    if (t == 0) part[blockIdx.x] = ls[0];
}

// phase B: single block exclusive-scans part[nb] in place (nb <= 256)
__global__ __launch_bounds__(256) void k_scan_b(int* __restrict__ part, int nb)
{
    __shared__ int ps[256];
    int t = threadIdx.x;
    int v = (t < nb) ? part[t] : 0;
    ps[t] = v;
    __syncthreads();
    #pragma unroll
    for (int off = 1; off < 256; off <<= 1) {
        int u = ps[t];
        if (t >= off) u += ps[t - off];
        __syncthreads();
        ps[t] = u;
        __syncthreads();
    }
    if (t < nb) part[t] = ps[t] - v;   // exclusive
}

// phase C: rescan with block offset -> rp, nxt; also dinv = rsqrt(deg+1)
__global__ __launch_bounds__(256) void k_scan_c(const int* __restrict__ deg,
    const int* __restrict__ part, int* __restrict__ rp, int* __restrict__ nxt,
    float* __restrict__ dinv, int N, int E)
{
    int base = blockIdx.x << 10;
    int t = threadIdx.x;
    int v[4];
    int ts = 0;
    #pragma unroll
    for (int j = 0; j < 4; ++j) {
        int i = base + t * 4 + j;
        v[j] = (i < N) ? deg[i] : 0;
        ts += v[j];
    }
    __shared__ int ps[256];
    ps[t] = ts;
    __syncthreads();
    #pragma unroll
    for (int off = 1; off < 256; off <<= 1) {
        int u = ps[t];
        if (t >= off) u += ps[t - off];
        __syncthreads();
        ps[t] = u;
        __syncthreads();
    }
    int run = part[blockIdx.x] + ps[t] - ts;   // exclusive offset for this thread
    #pragma unroll
    for (int j = 0; j < 4; ++j) {
        int i = base + t * 4 + j;
        if (i < N) {
            rp[i] = run;
            nxt[i] = run;
            dinv[i] = rsqrtf((float)(v[j] + 1));
            run += v[j];
        }
    }
    if (blockIdx.x == 0 && t == 0) rp[N] = E;
}

// ---------------- CSR fill: bucket src by dst ----------------
__global__ __launch_bounds__(256) void k_fill(const int* __restrict__ src,
    const int* __restrict__ dst, int* __restrict__ nxt, int* __restrict__ csr, int E)
{
    int stride = gridDim.x * blockDim.x;
    for (int e = blockIdx.x * blockDim.x + threadIdx.x; e < E; e += stride) {
        int p = atomicAdd(&nxt[dst[e]], 1);
        csr[p] = src[e];
    }
}

// ---------------- GEMM: Y[n][o] = dinv[n] * sum_k X[n][k]*W[o][k] ----------------
// LDS: wt (transposed W, 64KB) + xs (32-row tile, 16KB) = 80KB -> 2 blocks/CU
__global__ __launch_bounds__(256) void k_gemm128(const float* __restrict__ X,
    const float* __restrict__ W, const float* __restrict__ dinv,
    float* __restrict__ Y, int N)
{
    __shared__ float wt[NFEAT][NFEAT];   // wt[k][o] = W[o][k]
    __shared__ float xs[32][NFEAT];      // xs[r][k]
    for (int idx = threadIdx.x; idx < NFEAT * NFEAT; idx += 256) {
        int o = idx >> 7, k = idx & 127;
        wt[k][o] = W[idx];
    }
    int tx = threadIdx.x & 31;   // 4 cols: 4*tx .. 4*tx+3
    int ty = threadIdx.x >> 5;   // 4 rows: 4*ty .. 4*ty+3
    int ntiles = N >> 5;
    for (int tile = blockIdx.x; tile < ntiles; tile += gridDim.x) {
        int row0 = tile << 5;
        __syncthreads();   // also covers initial wt writes on first iter
        #pragma unroll
        for (int it = 0; it < 16; ++it) {
            int idx = it * 256 + threadIdx.x;
            int r = idx >> 7, k = idx & 127;
            xs[r][k] = X[(long)(row0 + r) * NFEAT + k];
        }
        __syncthreads();
        float acc[4][4];
        #pragma unroll
        for (int i = 0; i < 4; ++i)
            #pragma unroll
            for (int j = 0; j < 4; ++j) acc[i][j] = 0.f;
        #pragma unroll 4
        for (int k = 0; k < NFEAT; ++k) {
            float4 b = *(const float4*)&wt[k][tx * 4];
            float a0 = xs[ty * 4 + 0][k];
            float a1 = xs[ty * 4 + 1][k];
            float a2 = xs[ty * 4 + 2][k];
            float a3 = xs[ty * 4 + 3][k];
            acc[0][0] = fmaf(a0, b.x, acc[0][0]); acc[0][1] = fmaf(a0, b.y, acc[0][1]);
            acc[0][2] = fmaf(a0, b.z, acc[0][2]); acc[0][3] = fmaf(a0, b.w, acc[0][3]);
            acc[1][0] = fmaf(a1, b.x, acc[1][0]); acc[1][1] = fmaf(a1, b.y, acc[1][1]);
            acc[1][2] = fmaf(a1, b.z, acc[1][2]); acc[1][3] = fmaf(a1, b.w, acc[1][3]);
            acc[2][0] = fmaf(a2, b.x, acc[2][0]); acc[2][1] = fmaf(a2, b.y, acc[2][1]);
            acc[2][2] = fmaf(a2, b.z, acc[2][2]); acc[2][3] = fmaf(a2, b.w, acc[2][3]);
            acc[3][0] = fmaf(a3, b.x, acc[3][0]); acc[3][1] = fmaf(a3, b.y, acc[3][1]);
            acc[3][2] = fmaf(a3, b.z, acc[3][2]); acc[3][3] = fmaf(a3, b.w, acc[3][3]);
        }
        #pragma unroll
        for (int i = 0; i < 4; ++i) {
            int r = row0 + ty * 4 + i;
            float dv = dinv[r];
            float4 o = make_float4(acc[i][0] * dv, acc[i][1] * dv,
                                   acc[i][2] * dv, acc[i][3] * dv);
            *(float4*)&Y[(long)r * NFEAT + tx * 4] = o;
        }
    }
}

// ---------------- aggregation: out[v] = relu(dinv[v]*(tt[v] + sum_in tt[u]) + b) ----
// one wave per dst node, 2 cols (float2) per lane
__global__ __launch_bounds__(256) void k_agg(const float2* __restrict__ TT,
    const int* __restrict__ rp, const int* __restrict__ csr,
    const float* __restrict__ dinv, const float* __restrict__ bias,
    float2* __restrict__ OUT, int N)
{
    int wid = (blockIdx.x * 256 + threadIdx.x) >> 6;
    if (wid >= N) return;
    int lane = threadIdx.x & 63;
    long base = (long)wid * 64;
    float2 acc = TT[base + lane];   // self-loop term
    int e = rp[wid], e1 = rp[wid + 1];
    for (; e + 4 <= e1; e += 4) {
        int s0 = csr[e], s1 = csr[e + 1], s2 = csr[e + 2], s3 = csr[e + 3];
        float2 m0 = TT[(long)s0 * 64 + lane];
        float2 m1 = TT[(long)s1 * 64 + lane];
        float2 m2 = TT[(long)s2 * 64 + lane];
        float2 m3 = TT[(long)s3 * 64 + lane];
        acc.x += (m0.x + m1.x) + (m2.x + m3.x);
        acc.y += (m0.y + m1.y) + (m2.y + m3.y);
    }
    for (; e < e1; ++e) {
        int s = csr[e];
        float2 m = TT[(long)s * 64 + lane];
        acc.x += m.x; acc.y += m.y;
    }
    float dv = dinv[wid];
    float2 o;
    o.x = fmaxf(fmaf(acc.x, dv, bias[lane * 2 + 0]), 0.f);
    o.y = fmaxf(fmaf(acc.y, dv, bias[lane * 2 + 1]), 0.f);
    OUT[base + lane] = o;
}

// ---------------- fused head: relu(H@Wc1^T + bc1) @ Wc2^T + bc2 ----------------
__global__ __launch_bounds__(256) void k_head(const float* __restrict__ H,
    const float* __restrict__ Wc1, const float* __restrict__ bc1,
    const float* __restrict__ Wc2, const float* __restrict__ bc2,
    float* __restrict__ OUT, int N)
{
    __shared__ float w1[16][132];
    __shared__ float hs[16][132];
    __shared__ float h16[16][17];
    for (int idx = threadIdx.x; idx < 16 * NFEAT; idx += 256) {
        int o = idx >> 7, k = idx & 127;
        w1[o][k] = Wc1[idx];
    }
    int ntiles = (N + 15) >> 4;
    for (int tile = blockIdx.x; tile < ntiles; tile += gridDim.x) {
        int row0 = tile << 4;
        __syncthreads();   // also covers w1 init on first iter
        #pragma unroll
        for (int it = 0; it < 8; ++it) {
            int idx = it * 256 + threadIdx.x;
            int r = idx >> 7, k = idx & 127;
            int row = row0 + r;
            hs[r][k] = (row < N) ? H[(long)row * NFEAT + k] : 0.f;
        }
        __syncthreads();
        int r = threadIdx.x >> 4, o = threadIdx.x & 15;
        float acc = 0.f;
        #pragma unroll 8
        for (int k = 0; k < NFEAT; ++k) acc = fmaf(hs[r][k], w1[o][k], acc);
        h16[r][o] = fmaxf(acc + bc1[o], 0.f);
        __syncthreads();
        if (threadIdx.x < 32) {
            int rr = threadIdx.x >> 1, j = threadIdx.x & 1;
            float a = bc2[j];
            #pragma unroll
            for (int o2 = 0; o2 < 16; ++o2) a = fmaf(h16[rr][o2], Wc2[j * 16 + o2], a);
            int row = row0 + rr;
            if (row < N) OUT[(long)row * 2 + j] = a;
        }
        __syncthreads();
    }
}

extern "C" void kernel_launch(void* const* d_in, const int* in_sizes, int n_in,
                              void* d_out, int out_size, void* d_ws, size_t ws_size,
                              hipStream_t stream) {
    const float* x     = (const float*)d_in[0];
    const int*   ei    = (const int*)d_in[1];
    const float* gamma = (const float*)d_in[2];
    const float* beta  = (const float*)d_in[3];
    const float* W1    = (const float*)d_in[4];
    const float* b1    = (const float*)d_in[5];
    const float* W2    = (const float*)d_in[6];
    const float* b2    = (const float*)d_in[7];
    const float* Wc1   = (const float*)d_in[8];
    const float* bc1   = (const float*)d_in[9];
    const float* Wc2   = (const float*)d_in[10];
    const float* bc2   = (const float*)d_in[11];

    int N = in_sizes[0] / NFEAT;
    int E = in_sizes[1] / 2;
    const int* srcI = ei;
    const int* dstI = ei + E;

    char* ws = (char*)d_ws;
    size_t off = 0;
    auto alloc = [&](size_t bytes) {
        void* p = ws + off;
        off += bytes;
        off = (off + 511) & ~(size_t)511;
        return p;
    };
    float* buf0  = (float*)alloc((size_t)N * NFEAT * 4);
    float* buf1  = (float*)alloc((size_t)N * NFEAT * 4);
    float* sum   = (float*)alloc(NFEAT * 4);
    float* sumsq = (float*)alloc(NFEAT * 4);
    int*   deg   = (int*)alloc((size_t)N * 4);
    int*   rp    = (int*)alloc((size_t)(N + 1) * 4);
    int*   nxt   = (int*)alloc((size_t)N * 4);
    float* dinv  = (float*)alloc((size_t)N * 4);
    int*   csr   = (int*)alloc((size_t)E * 4);
    int*   part  = (int*)alloc(256 * 4);
    (void)ws_size;

    hipMemsetAsync(sum, 0, NFEAT * 4, stream);
    hipMemsetAsync(sumsq, 0, NFEAT * 4, stream);
    hipMemsetAsync(deg, 0, (size_t)N * 4, stream);

    long total = (long)N * NFEAT;
    int nb = (N + 1023) >> 10;   // 98 blocks for N=100k
    k_stats<<<1024, 256, 0, stream>>>(x, sum, sumsq, total);
    k_bn<<<2048, 256, 0, stream>>>(x, sum, sumsq, gamma, beta, buf0, total >> 2, 1.0f / (float)N);
    k_deg<<<1024, 256, 0, stream>>>(dstI, deg, E);
    k_scan_a<<<nb, 256, 0, stream>>>(deg, part, N);
    k_scan_b<<<1, 256, 0, stream>>>(part, nb);
    k_scan_c<<<nb, 256, 0, stream>>>(deg, part, rp, nxt, dinv, N, E);
    k_fill<<<1024, 256, 0, stream>>>(srcI, dstI, nxt, csr, E);

    // layer 1
    k_gemm128<<<1024, 256, 0, stream>>>(buf0, W1, dinv, buf1, N);
    k_agg<<<(N + 3) / 4, 256, 0, stream>>>((const float2*)buf1, rp, csr, dinv, b1, (float2*)buf0, N);
    // layer 2
    k_gemm128<<<1024, 256, 0, stream>>>(buf0, W2, dinv, buf1, N);
    k_agg<<<(N + 3) / 4, 256, 0, stream>>>((const float2*)buf1, rp, csr, dinv, b2, (float2*)buf0, N);
    // head
    k_head<<<2048, 256, 0, stream>>>(buf0, Wc1, bc1, Wc2, bc2, (float*)d_out, N);
}

// Round 3
// 555.330 us; speedup vs baseline: 1.6053x; 1.2424x over previous
//
#include <hip/hip_runtime.h>

#define NFEAT 128
#define EPSV 1e-5f
#define BSH 9
#define BSZ 512   // nodes per dst-bucket

// ---------------- column stats (mean/var over N rows, 128 cols) ----------------
__global__ __launch_bounds__(256) void k_stats(const float* __restrict__ X,
    float* __restrict__ sum, float* __restrict__ sumsq, long total)
{
    float s = 0.f, q = 0.f;
    long stride = (long)gridDim.x * blockDim.x;
    for (long i = (long)blockIdx.x * blockDim.x + threadIdx.x; i < total; i += stride) {
        float v = X[i];
        s += v;
        q = fmaf(v, v, q);
    }
    __shared__ float ls[256], lq[256];
    ls[threadIdx.x] = s; lq[threadIdx.x] = q;
    __syncthreads();
    if (threadIdx.x < 128) {
        int c = threadIdx.x;            // stride is a multiple of 128 -> col == tid&127
        s = ls[c] + ls[c + 128];
        q = lq[c] + lq[c + 128];
        unsafeAtomicAdd(&sum[c], s);
        unsafeAtomicAdd(&sumsq[c], q);
    }
}

// ---------------- BN apply: xn = (x-mu)*rstd*gamma + beta ----------------
__global__ __launch_bounds__(256) void k_bn(const float* __restrict__ X,
    const float* __restrict__ sum, const float* __restrict__ sumsq,
    const float* __restrict__ gamma, const float* __restrict__ beta,
    float* __restrict__ XN, long total4, float invN)
{
    __shared__ float sc[NFEAT], sh[NFEAT];
    if (threadIdx.x < NFEAT) {
        int c = threadIdx.x;
        float mu = sum[c] * invN;
        float var = fmaf(-mu, mu, sumsq[c] * invN);
        float r = rsqrtf(var + EPSV);
        float g = r * gamma[c];
        sc[c] = g;
        sh[c] = fmaf(-mu, g, beta[c]);
    }
    __syncthreads();
    const float4* X4 = (const float4*)X;
    float4* XN4 = (float4*)XN;
    long stride = (long)gridDim.x * blockDim.x;
    for (long i = (long)blockIdx.x * blockDim.x + threadIdx.x; i < total4; i += stride) {
        int c0 = (int)((i << 2) & (NFEAT - 1));
        float4 v = X4[i];
        float4 o;
        o.x = fmaf(v.x, sc[c0 + 0], sh[c0 + 0]);
        o.y = fmaf(v.y, sc[c0 + 1], sh[c0 + 1]);
        o.z = fmaf(v.z, sc[c0 + 2], sh[c0 + 2]);
        o.w = fmaf(v.w, sc[c0 + 3], sh[c0 + 3]);
        XN4[i] = o;
    }
}

// ---------------- bucket histogram over dst>>BSH ----------------
__global__ __launch_bounds__(256) void k_bhist(const int* __restrict__ dst,
    int* __restrict__ bcnt, int E, int NB)
{
    __shared__ int hist[1024];
    for (int i = threadIdx.x; i < NB; i += 256) hist[i] = 0;
    __syncthreads();
    int stride = gridDim.x * 256;
    for (int e = blockIdx.x * 256 + threadIdx.x; e < E; e += stride)
        atomicAdd(&hist[dst[e] >> BSH], 1);
    __syncthreads();
    for (int i = threadIdx.x; i < NB; i += 256)
        if (hist[i]) atomicAdd(&bcnt[i], hist[i]);
}

// ---------------- scan bucket counts (NB <= 256) -> boff[NB+1], bnxt ----------------
__global__ __launch_bounds__(256) void k_bscan(const int* __restrict__ bcnt,
    int* __restrict__ boff, int* __restrict__ bnxt, int NB)
{
    __shared__ int ps[256];
    int t = threadIdx.x;
    int v = (t < NB) ? bcnt[t] : 0;
    ps[t] = v;
    __syncthreads();
    #pragma unroll
    for (int off = 1; off < 256; off <<= 1) {
        int u = ps[t];
        if (t >= off) u += ps[t - off];
        __syncthreads();
        ps[t] = u;
        __syncthreads();
    }
    if (t < NB) {
        int ex = ps[t] - v;
        boff[t] = ex;
        bnxt[t] = ex;
    }
    if (t == NB - 1) boff[NB] = ps[t];
}

// ---------------- partition edges into buckets, packed (src<<BSH | dst&511) ----------
__global__ __launch_bounds__(256) void k_bucket(const int* __restrict__ src,
    const int* __restrict__ dst, int* __restrict__ bnxt,
    int* __restrict__ packed, int E, int NB)
{
    __shared__ int hist[1024];
    __shared__ int base[1024];
    int c0 = blockIdx.x * 8192;
    int c1 = min(E, c0 + 8192);
    for (int i = threadIdx.x; i < NB; i += 256) hist[i] = 0;
    __syncthreads();
    for (int e = c0 + threadIdx.x; e < c1; e += 256)
        atomicAdd(&hist[dst[e] >> BSH], 1);
    __syncthreads();
    for (int i = threadIdx.x; i < NB; i += 256) {
        int h = hist[i];
        base[i] = h ? atomicAdd(&bnxt[i], h) : 0;
        hist[i] = 0;
    }
    __syncthreads();
    for (int e = c0 + threadIdx.x; e < c1; e += 256) {
        int d = dst[e];
        int b = d >> BSH;
        int p = base[b] + atomicAdd(&hist[b], 1);
        packed[p] = (src[e] << BSH) | (d & (BSZ - 1));
    }
}

// ---------------- per-bucket degree (LDS counters -> coalesced deg writes) --------
__global__ __launch_bounds__(256) void k_bdeg(const int* __restrict__ packed,
    const int* __restrict__ boff, int* __restrict__ deg, int N)
{
    __shared__ int cnt[BSZ];
    int b = blockIdx.x;
    for (int i = threadIdx.x; i < BSZ; i += 256) cnt[i] = 0;
    __syncthreads();
    int e0 = boff[b], e1 = boff[b + 1];
    for (int e = e0 + threadIdx.x; e < e1; e += 256)
        atomicAdd(&cnt[packed[e] & (BSZ - 1)], 1);
    __syncthreads();
    int nbase = b << BSH;
    for (int i = threadIdx.x; i < BSZ; i += 256)
        if (nbase + i < N) deg[nbase + i] = cnt[i];
}

// ---------------- 3-phase device-wide exclusive scan ----------------
__global__ __launch_bounds__(256) void k_scan_a(const int* __restrict__ deg,
    int* __restrict__ part, int N)
{
    int base = blockIdx.x << 10;
    int t = threadIdx.x;
    int s = 0;
    #pragma unroll
    for (int j = 0; j < 4; ++j) {
        int i = base + t * 4 + j;
        if (i < N) s += deg[i];
    }
    __shared__ int ls[256];
    ls[t] = s;
    __syncthreads();
    #pragma unroll
    for (int off = 128; off > 0; off >>= 1) {
        if (t < off) ls[t] += ls[t + off];
        __syncthreads();
    }
    if (t == 0) part[blockIdx.x] = ls[0];
}

__global__ __launch_bounds__(256) void k_scan_b(int* __restrict__ part, int nb)
{
    __shared__ int ps[256];
    int t = threadIdx.x;
    int v = (t < nb) ? part[t] : 0;
    ps[t] = v;
    __syncthreads();
    #pragma unroll
    for (int off = 1; off < 256; off <<= 1) {
        int u = ps[t];
        if (t >= off) u += ps[t - off];
        __syncthreads();
        ps[t] = u;
        __syncthreads();
    }
    if (t < nb) part[t] = ps[t] - v;   // exclusive
}

__global__ __launch_bounds__(256) void k_scan_c(const int* __restrict__ deg,
    const int* __restrict__ part, int* __restrict__ rp,
    float* __restrict__ dinv, int N, int E)
{
    int base = blockIdx.x << 10;
    int t = threadIdx.x;
    int v[4];
    int ts = 0;
    #pragma unroll
    for (int j = 0; j < 4; ++j) {
        int i = base + t * 4 + j;
        v[j] = (i < N) ? deg[i] : 0;
        ts += v[j];
    }
    __shared__ int ps[256];
    ps[t] = ts;
    __syncthreads();
    #pragma unroll
    for (int off = 1; off < 256; off <<= 1) {
        int u = ps[t];
        if (t >= off) u += ps[t - off];
        __syncthreads();
        ps[t] = u;
        __syncthreads();
    }
    int run = part[blockIdx.x] + ps[t] - ts;   // exclusive offset for this thread
    #pragma unroll
    for (int j = 0; j < 4; ++j) {
        int i = base + t * 4 + j;
        if (i < N) {
            rp[i] = run;
            dinv[i] = rsqrtf((float)(v[j] + 1));
            run += v[j];
        }
    }
    if (blockIdx.x == 0 && t == 0) rp[N] = E;
}

// ---------------- per-bucket CSR placement (writes confined to 33KB window) ------
__global__ __launch_bounds__(256) void k_place(const int* __restrict__ packed,
    const int* __restrict__ boff, const int* __restrict__ rp,
    int* __restrict__ csr, int N)
{
    __shared__ int nxt[BSZ];
    int b = blockIdx.x;
    int nbase = b << BSH;
    for (int i = threadIdx.x; i < BSZ; i += 256)
        nxt[i] = (nbase + i < N) ? rp[nbase + i] : 0;
    __syncthreads();
    int e0 = boff[b], e1 = boff[b + 1];
    for (int e = e0 + threadIdx.x; e < e1; e += 256) {
        int v = packed[e];
        int p = atomicAdd(&nxt[v & (BSZ - 1)], 1);
        csr[p] = v >> BSH;
    }
}

// ---------------- GEMM: Y[n][o] = dinv[n] * sum_k X[n][k]*W[o][k] ----------------
__global__ __launch_bounds__(256) void k_gemm128(const float* __restrict__ X,
    const float* __restrict__ W, const float* __restrict__ dinv,
    float* __restrict__ Y, int N)
{
    __shared__ float wt[NFEAT][NFEAT];   // wt[k][o] = W[o][k]
    __shared__ float xs[32][NFEAT];      // xs[r][k]
    for (int idx = threadIdx.x; idx < NFEAT * NFEAT; idx += 256) {
        int o = idx >> 7, k = idx & 127;
        wt[k][o] = W[idx];
    }
    int tx = threadIdx.x & 31;   // 4 cols: 4*tx .. 4*tx+3
    int ty = threadIdx.x >> 5;   // 4 rows: 4*ty .. 4*ty+3
    int ntiles = N >> 5;
    for (int tile = blockIdx.x; tile < ntiles; tile += gridDim.x) {
        int row0 = tile << 5;
        __syncthreads();   // also covers initial wt writes on first iter
        #pragma unroll
        for (int it = 0; it < 16; ++it) {
            int idx = it * 256 + threadIdx.x;
            int r = idx >> 7, k = idx & 127;
            xs[r][k] = X[(long)(row0 + r) * NFEAT + k];
        }
        __syncthreads();
        float acc[4][4];
        #pragma unroll
        for (int i = 0; i < 4; ++i)
            #pragma unroll
            for (int j = 0; j < 4; ++j) acc[i][j] = 0.f;
        #pragma unroll 4
        for (int k = 0; k < NFEAT; ++k) {
            float4 b = *(const float4*)&wt[k][tx * 4];
            float a0 = xs[ty * 4 + 0][k];
            float a1 = xs[ty * 4 + 1][k];
            float a2 = xs[ty * 4 + 2][k];
            float a3 = xs[ty * 4 + 3][k];
            acc[0][0] = fmaf(a0, b.x, acc[0][0]); acc[0][1] = fmaf(a0, b.y, acc[0][1]);
            acc[0][2] = fmaf(a0, b.z, acc[0][2]); acc[0][3] = fmaf(a0, b.w, acc[0][3]);
            acc[1][0] = fmaf(a1, b.x, acc[1][0]); acc[1][1] = fmaf(a1, b.y, acc[1][1]);
            acc[1][2] = fmaf(a1, b.z, acc[1][2]); acc[1][3] = fmaf(a1, b.w, acc[1][3]);
            acc[2][0] = fmaf(a2, b.x, acc[2][0]); acc[2][1] = fmaf(a2, b.y, acc[2][1]);
            acc[2][2] = fmaf(a2, b.z, acc[2][2]); acc[2][3] = fmaf(a2, b.w, acc[2][3]);
            acc[3][0] = fmaf(a3, b.x, acc[3][0]); acc[3][1] = fmaf(a3, b.y, acc[3][1]);
            acc[3][2] = fmaf(a3, b.z, acc[3][2]); acc[3][3] = fmaf(a3, b.w, acc[3][3]);
        }
        #pragma unroll
        for (int i = 0; i < 4; ++i) {
            int r = row0 + ty * 4 + i;
            float dv = dinv[r];
            float4 o = make_float4(acc[i][0] * dv, acc[i][1] * dv,
                                   acc[i][2] * dv, acc[i][3] * dv);
            *(float4*)&Y[(long)r * NFEAT + tx * 4] = o;
        }
    }
}

// ---------------- aggregation: out[v] = relu(dinv[v]*(tt[v] + sum_in tt[u]) + b) ----
__global__ __launch_bounds__(256) void k_agg(const float2* __restrict__ TT,
    const int* __restrict__ rp, const int* __restrict__ csr,
    const float* __restrict__ dinv, const float* __restrict__ bias,
    float2* __restrict__ OUT, int N)
{
    int wid = (blockIdx.x * 256 + threadIdx.x) >> 6;
    if (wid >= N) return;
    int lane = threadIdx.x & 63;
    long base = (long)wid * 64;
    float2 acc = TT[base + lane];   // self-loop term
    int e = rp[wid], e1 = rp[wid + 1];
    for (; e + 4 <= e1; e += 4) {
        int s0 = csr[e], s1 = csr[e + 1], s2 = csr[e + 2], s3 = csr[e + 3];
        float2 m0 = TT[(long)s0 * 64 + lane];
        float2 m1 = TT[(long)s1 * 64 + lane];
        float2 m2 = TT[(long)s2 * 64 + lane];
        float2 m3 = TT[(long)s3 * 64 + lane];
        acc.x += (m0.x + m1.x) + (m2.x + m3.x);
        acc.y += (m0.y + m1.y) + (m2.y + m3.y);
    }
    for (; e < e1; ++e) {
        int s = csr[e];
        float2 m = TT[(long)s * 64 + lane];
        acc.x += m.x; acc.y += m.y;
    }
    float dv = dinv[wid];
    float2 o;
    o.x = fmaxf(fmaf(acc.x, dv, bias[lane * 2 + 0]), 0.f);
    o.y = fmaxf(fmaf(acc.y, dv, bias[lane * 2 + 1]), 0.f);
    OUT[base + lane] = o;
}

// ---------------- fused head: relu(H@Wc1^T + bc1) @ Wc2^T + bc2 ----------------
__global__ __launch_bounds__(256) void k_head(const float* __restrict__ H,
    const float* __restrict__ Wc1, const float* __restrict__ bc1,
    const float* __restrict__ Wc2, const float* __restrict__ bc2,
    float* __restrict__ OUT, int N)
{
    __shared__ float w1[16][132];
    __shared__ float hs[16][132];
    __shared__ float h16[16][17];
    for (int idx = threadIdx.x; idx < 16 * NFEAT; idx += 256) {
        int o = idx >> 7, k = idx & 127;
        w1[o][k] = Wc1[idx];
    }
    int ntiles = (N + 15) >> 4;
    for (int tile = blockIdx.x; tile < ntiles; tile += gridDim.x) {
        int row0 = tile << 4;
        __syncthreads();   // also covers w1 init on first iter
        #pragma unroll
        for (int it = 0; it < 8; ++it) {
            int idx = it * 256 + threadIdx.x;
            int r = idx >> 7, k = idx & 127;
            int row = row0 + r;
            hs[r][k] = (row < N) ? H[(long)row * NFEAT + k] : 0.f;
        }
        __syncthreads();
        int r = threadIdx.x >> 4, o = threadIdx.x & 15;
        float acc = 0.f;
        #pragma unroll 8
        for (int k = 0; k < NFEAT; ++k) acc = fmaf(hs[r][k], w1[o][k], acc);
        h16[r][o] = fmaxf(acc + bc1[o], 0.f);
        __syncthreads();
        if (threadIdx.x < 32) {
            int rr = threadIdx.x >> 1, j = threadIdx.x & 1;
            float a = bc2[j];
            #pragma unroll
            for (int o2 = 0; o2 < 16; ++o2) a = fmaf(h16[rr][o2], Wc2[j * 16 + o2], a);
            int row = row0 + rr;
            if (row < N) OUT[(long)row * 2 + j] = a;
        }
        __syncthreads();
    }
}

extern "C" void kernel_launch(void* const* d_in, const int* in_sizes, int n_in,
                              void* d_out, int out_size, void* d_ws, size_t ws_size,
                              hipStream_t stream) {
    const float* x     = (const float*)d_in[0];
    const int*   ei    = (const int*)d_in[1];
    const float* gamma = (const float*)d_in[2];
    const float* beta  = (const float*)d_in[3];
    const float* W1    = (const float*)d_in[4];
    const float* b1    = (const float*)d_in[5];
    const float* W2    = (const float*)d_in[6];
    const float* b2    = (const float*)d_in[7];
    const float* Wc1   = (const float*)d_in[8];
    const float* bc1   = (const float*)d_in[9];
    const float* Wc2   = (const float*)d_in[10];
    const float* bc2   = (const float*)d_in[11];

    int N = in_sizes[0] / NFEAT;
    int E = in_sizes[1] / 2;
    const int* srcI = ei;
    const int* dstI = ei + E;
    int NB = (N + BSZ - 1) >> BSH;   // 196 for N=100k (<=256 required by k_bscan)

    char* ws = (char*)d_ws;
    size_t off = 0;
    auto alloc = [&](size_t bytes) {
        void* p = ws + off;
        off += bytes;
        off = (off + 511) & ~(size_t)511;
        return p;
    };
    float* buf0   = (float*)alloc((size_t)N * NFEAT * 4);
    float* buf1   = (float*)alloc((size_t)N * NFEAT * 4);
    float* sum    = (float*)alloc(NFEAT * 4);
    float* sumsq  = (float*)alloc(NFEAT * 4);
    int*   deg    = (int*)alloc((size_t)N * 4);
    int*   rp     = (int*)alloc((size_t)(N + 1) * 4);
    float* dinv   = (float*)alloc((size_t)N * 4);
    int*   csr    = (int*)alloc((size_t)E * 4);
    int*   packed = (int*)alloc((size_t)E * 4);
    int*   bcnt   = (int*)alloc((size_t)(NB + 1) * 4);
    int*   boff   = (int*)alloc((size_t)(NB + 1) * 4);
    int*   bnxt   = (int*)alloc((size_t)(NB + 1) * 4);
    int*   part   = (int*)alloc(256 * 4);
    (void)ws_size;

    hipMemsetAsync(sum, 0, NFEAT * 4, stream);
    hipMemsetAsync(sumsq, 0, NFEAT * 4, stream);
    hipMemsetAsync(bcnt, 0, (size_t)(NB + 1) * 4, stream);

    long total = (long)N * NFEAT;
    int nb = (N + 1023) >> 10;          // scan blocks
    int nchunk = (E + 8191) >> 13;      // bucket partition blocks (8192 edges each)

    k_stats<<<1024, 256, 0, stream>>>(x, sum, sumsq, total);
    k_bn<<<2048, 256, 0, stream>>>(x, sum, sumsq, gamma, beta, buf0, total >> 2, 1.0f / (float)N);

    // graph build (bucketed counting sort, L2-window scatter)
    k_bhist<<<NB, 256, 0, stream>>>(dstI, bcnt, E, NB);
    k_bscan<<<1, 256, 0, stream>>>(bcnt, boff, bnxt, NB);
    k_bucket<<<nchunk, 256, 0, stream>>>(srcI, dstI, bnxt, packed, E, NB);
    k_bdeg<<<NB, 256, 0, stream>>>(packed, boff, deg, N);
    k_scan_a<<<nb, 256, 0, stream>>>(deg, part, N);
    k_scan_b<<<1, 256, 0, stream>>>(part, nb);
    k_scan_c<<<nb, 256, 0, stream>>>(deg, part, rp, dinv, N, E);
    k_place<<<NB, 256, 0, stream>>>(packed, boff, rp, csr, N);

    // layer 1
    k_gemm128<<<1024, 256, 0, stream>>>(buf0, W1, dinv, buf1, N);
    k_agg<<<(N + 3) / 4, 256, 0, stream>>>((const float2*)buf1, rp, csr, dinv, b1, (float2*)buf0, N);
    // layer 2
    k_gemm128<<<1024, 256, 0, stream>>>(buf0, W2, dinv, buf1, N);
    k_agg<<<(N + 3) / 4, 256, 0, stream>>>((const float2*)buf1, rp, csr, dinv, b2, (float2*)buf0, N);
    // head
    k_head<<<2048, 256, 0, stream>>>(buf0, Wc1, bc1, Wc2, bc2, (float*)d_out, N);
}

// Round 4
// 419.193 us; speedup vs baseline: 2.1266x; 1.3248x over previous
//
#include <hip/hip_runtime.h>
#include <hip/hip_fp16.h>

#define NFEAT 128
#define EPSV 1e-5f
#define BSH 9
#define BSZ 512   // nodes per dst-bucket

// ---------------- column stats (mean/var over N rows, 128 cols) ----------------
__global__ __launch_bounds__(256) void k_stats(const float* __restrict__ X,
    float* __restrict__ sum, float* __restrict__ sumsq, long total)
{
    float s = 0.f, q = 0.f;
    long stride = (long)gridDim.x * blockDim.x;
    for (long i = (long)blockIdx.x * blockDim.x + threadIdx.x; i < total; i += stride) {
        float v = X[i];
        s += v;
        q = fmaf(v, v, q);
    }
    __shared__ float ls[256], lq[256];
    ls[threadIdx.x] = s; lq[threadIdx.x] = q;
    __syncthreads();
    if (threadIdx.x < 128) {
        int c = threadIdx.x;            // stride is a multiple of 128 -> col == tid&127
        s = ls[c] + ls[c + 128];
        q = lq[c] + lq[c + 128];
        unsafeAtomicAdd(&sum[c], s);
        unsafeAtomicAdd(&sumsq[c], q);
    }
}

// ---------------- BN apply: xn = (x-mu)*rstd*gamma + beta  (write f16) ----------
__global__ __launch_bounds__(256) void k_bn(const float* __restrict__ X,
    const float* __restrict__ sum, const float* __restrict__ sumsq,
    const float* __restrict__ gamma, const float* __restrict__ beta,
    __half* __restrict__ XN, long total4, float invN)
{
    __shared__ float sc[NFEAT], sh[NFEAT];
    if (threadIdx.x < NFEAT) {
        int c = threadIdx.x;
        float mu = sum[c] * invN;
        float var = fmaf(-mu, mu, sumsq[c] * invN);
        float r = rsqrtf(var + EPSV);
        float g = r * gamma[c];
        sc[c] = g;
        sh[c] = fmaf(-mu, g, beta[c]);
    }
    __syncthreads();
    const float4* X4 = (const float4*)X;
    uint2* XN4 = (uint2*)XN;
    long stride = (long)gridDim.x * blockDim.x;
    for (long i = (long)blockIdx.x * blockDim.x + threadIdx.x; i < total4; i += stride) {
        int c0 = (int)((i << 2) & (NFEAT - 1));
        float4 v = X4[i];
        float4 o;
        o.x = fmaf(v.x, sc[c0 + 0], sh[c0 + 0]);
        o.y = fmaf(v.y, sc[c0 + 1], sh[c0 + 1]);
        o.z = fmaf(v.z, sc[c0 + 2], sh[c0 + 2]);
        o.w = fmaf(v.w, sc[c0 + 3], sh[c0 + 3]);
        __half2 h0 = __floats2half2_rn(o.x, o.y);
        __half2 h1 = __floats2half2_rn(o.z, o.w);
        uint2 u;
        u.x = *(unsigned int*)&h0;
        u.y = *(unsigned int*)&h1;
        XN4[i] = u;
    }
}

// ---------------- bucket histogram over dst>>BSH ----------------
__global__ __launch_bounds__(256) void k_bhist(const int* __restrict__ dst,
    int* __restrict__ bcnt, int E, int NB)
{
    __shared__ int hist[1024];
    for (int i = threadIdx.x; i < NB; i += 256) hist[i] = 0;
    __syncthreads();
    int stride = gridDim.x * 256;
    for (int e = blockIdx.x * 256 + threadIdx.x; e < E; e += stride)
        atomicAdd(&hist[dst[e] >> BSH], 1);
    __syncthreads();
    for (int i = threadIdx.x; i < NB; i += 256)
        if (hist[i]) atomicAdd(&bcnt[i], hist[i]);
}

// ---------------- scan bucket counts (NB <= 256) -> boff[NB+1], bnxt ----------------
__global__ __launch_bounds__(256) void k_bscan(const int* __restrict__ bcnt,
    int* __restrict__ boff, int* __restrict__ bnxt, int NB)
{
    __shared__ int ps[256];
    int t = threadIdx.x;
    int v = (t < NB) ? bcnt[t] : 0;
    ps[t] = v;
    __syncthreads();
    #pragma unroll
    for (int off = 1; off < 256; off <<= 1) {
        int u = ps[t];
        if (t >= off) u += ps[t - off];
        __syncthreads();
        ps[t] = u;
        __syncthreads();
    }
    if (t < NB) {
        int ex = ps[t] - v;
        boff[t] = ex;
        bnxt[t] = ex;
    }
    if (t == NB - 1) boff[NB] = ps[t];
}

// ---------------- partition edges into buckets, packed (src<<BSH | dst&511) ----------
__global__ __launch_bounds__(256) void k_bucket(const int* __restrict__ src,
    const int* __restrict__ dst, int* __restrict__ bnxt,
    int* __restrict__ packed, int E, int NB)
{
    __shared__ int hist[1024];
    __shared__ int base[1024];
    int c0 = blockIdx.x * 8192;
    int c1 = min(E, c0 + 8192);
    for (int i = threadIdx.x; i < NB; i += 256) hist[i] = 0;
    __syncthreads();
    for (int e = c0 + threadIdx.x; e < c1; e += 256)
        atomicAdd(&hist[dst[e] >> BSH], 1);
    __syncthreads();
    for (int i = threadIdx.x; i < NB; i += 256) {
        int h = hist[i];
        base[i] = h ? atomicAdd(&bnxt[i], h) : 0;
        hist[i] = 0;
    }
    __syncthreads();
    for (int e = c0 + threadIdx.x; e < c1; e += 256) {
        int d = dst[e];
        int b = d >> BSH;
        int p = base[b] + atomicAdd(&hist[b], 1);
        packed[p] = (src[e] << BSH) | (d & (BSZ - 1));
    }
}

// ---------------- per-bucket degree (LDS counters -> coalesced deg writes) --------
__global__ __launch_bounds__(256) void k_bdeg(const int* __restrict__ packed,
    const int* __restrict__ boff, int* __restrict__ deg, int N)
{
    __shared__ int cnt[BSZ];
    int b = blockIdx.x;
    for (int i = threadIdx.x; i < BSZ; i += 256) cnt[i] = 0;
    __syncthreads();
    int e0 = boff[b], e1 = boff[b + 1];
    for (int e = e0 + threadIdx.x; e < e1; e += 256)
        atomicAdd(&cnt[packed[e] & (BSZ - 1)], 1);
    __syncthreads();
    int nbase = b << BSH;
    for (int i = threadIdx.x; i < BSZ; i += 256)
        if (nbase + i < N) deg[nbase + i] = cnt[i];
}

// ---------------- 3-phase device-wide exclusive scan ----------------
__global__ __launch_bounds__(256) void k_scan_a(const int* __restrict__ deg,
    int* __restrict__ part, int N)
{
    int base = blockIdx.x << 10;
    int t = threadIdx.x;
    int s = 0;
    #pragma unroll
    for (int j = 0; j < 4; ++j) {
        int i = base + t * 4 + j;
        if (i < N) s += deg[i];
    }
    __shared__ int ls[256];
    ls[t] = s;
    __syncthreads();
    #pragma unroll
    for (int off = 128; off > 0; off >>= 1) {
        if (t < off) ls[t] += ls[t + off];
        __syncthreads();
    }
    if (t == 0) part[blockIdx.x] = ls[0];
}

__global__ __launch_bounds__(256) void k_scan_b(int* __restrict__ part, int nb)
{
    __shared__ int ps[256];
    int t = threadIdx.x;
    int v = (t < nb) ? part[t] : 0;
    ps[t] = v;
    __syncthreads();
    #pragma unroll
    for (int off = 1; off < 256; off <<= 1) {
        int u = ps[t];
        if (t >= off) u += ps[t - off];
        __syncthreads();
        ps[t] = u;
        __syncthreads();
    }
    if (t < nb) part[t] = ps[t] - v;   // exclusive
}

__global__ __launch_bounds__(256) void k_scan_c(const int* __restrict__ deg,
    const int* __restrict__ part, int* __restrict__ rp,
    float* __restrict__ dinv, int N, int E)
{
    int base = blockIdx.x << 10;
    int t = threadIdx.x;
    int v[4];
    int ts = 0;
    #pragma unroll
    for (int j = 0; j < 4; ++j) {
        int i = base + t * 4 + j;
        v[j] = (i < N) ? deg[i] : 0;
        ts += v[j];
    }
    __shared__ int ps[256];
    ps[t] = ts;
    __syncthreads();
    #pragma unroll
    for (int off = 1; off < 256; off <<= 1) {
        int u = ps[t];
        if (t >= off) u += ps[t - off];
        __syncthreads();
        ps[t] = u;
        __syncthreads();
    }
    int run = part[blockIdx.x] + ps[t] - ts;   // exclusive offset for this thread
    #pragma unroll
    for (int j = 0; j < 4; ++j) {
        int i = base + t * 4 + j;
        if (i < N) {
            rp[i] = run;
            dinv[i] = rsqrtf((float)(v[j] + 1));
            run += v[j];
        }
    }
    if (blockIdx.x == 0 && t == 0) rp[N] = E;
}

// ---------------- per-bucket CSR placement (writes confined to 33KB window) ------
__global__ __launch_bounds__(256) void k_place(const int* __restrict__ packed,
    const int* __restrict__ boff, const int* __restrict__ rp,
    int* __restrict__ csr, int N)
{
    __shared__ int nxt[BSZ];
    int b = blockIdx.x;
    int nbase = b << BSH;
    for (int i = threadIdx.x; i < BSZ; i += 256)
        nxt[i] = (nbase + i < N) ? rp[nbase + i] : 0;
    __syncthreads();
    int e0 = boff[b], e1 = boff[b + 1];
    for (int e = e0 + threadIdx.x; e < e1; e += 256) {
        int v = packed[e];
        int p = atomicAdd(&nxt[v & (BSZ - 1)], 1);
        csr[p] = v >> BSH;
    }
}

// ---------------- GEMM: Y[n][o] = dinv[n] * sum_k X[n][k]*W[o][k]  (f16 in/out) --
// wt staging XOR-swizzled (chunk-granular) to kill the 64-way transpose conflict;
// hot-loop float4 reads stay 16B-aligned and conflict-free.
__global__ __launch_bounds__(256) void k_gemm128(const __half* __restrict__ X,
    const float* __restrict__ W, const float* __restrict__ dinv,
    __half* __restrict__ Y, int N)
{
    __shared__ float wt[NFEAT][NFEAT];   // wt[k][o ^ ((k&7)<<2)] = W[o][k]
    __shared__ float xs[32][NFEAT];      // xs[r][k]
    for (int idx = threadIdx.x; idx < NFEAT * NFEAT; idx += 256) {
        int o = idx >> 7, k = idx & 127;
        wt[k][o ^ ((k & 7) << 2)] = W[idx];
    }
    const unsigned int* Xu = (const unsigned int*)X;   // half2 view, 64 per row
    int tx = threadIdx.x & 31;   // 4 cols: 4*tx .. 4*tx+3
    int ty = threadIdx.x >> 5;   // 4 rows: 4*ty .. 4*ty+3
    int ntiles = N >> 5;
    for (int tile = blockIdx.x; tile < ntiles; tile += gridDim.x) {
        int row0 = tile << 5;
        __syncthreads();   // also covers initial wt writes on first iter
        #pragma unroll
        for (int it = 0; it < 8; ++it) {
            int idx = it * 256 + threadIdx.x;   // 0..2047
            int r = idx >> 6, p = idx & 63;
            unsigned int v = Xu[(long)(row0 + r) * 64 + p];
            float2 f = __half22float2(*(const __half2*)&v);
            xs[r][p * 2] = f.x;
            xs[r][p * 2 + 1] = f.y;
        }
        __syncthreads();
        float acc[4][4];
        #pragma unroll
        for (int i = 0; i < 4; ++i)
            #pragma unroll
            for (int j = 0; j < 4; ++j) acc[i][j] = 0.f;
        #pragma unroll 4
        for (int k = 0; k < NFEAT; ++k) {
            float4 b = *(const float4*)&wt[k][(tx * 4) ^ ((k & 7) << 2)];
            float a0 = xs[ty * 4 + 0][k];
            float a1 = xs[ty * 4 + 1][k];
            float a2 = xs[ty * 4 + 2][k];
            float a3 = xs[ty * 4 + 3][k];
            acc[0][0] = fmaf(a0, b.x, acc[0][0]); acc[0][1] = fmaf(a0, b.y, acc[0][1]);
            acc[0][2] = fmaf(a0, b.z, acc[0][2]); acc[0][3] = fmaf(a0, b.w, acc[0][3]);
            acc[1][0] = fmaf(a1, b.x, acc[1][0]); acc[1][1] = fmaf(a1, b.y, acc[1][1]);
            acc[1][2] = fmaf(a1, b.z, acc[1][2]); acc[1][3] = fmaf(a1, b.w, acc[1][3]);
            acc[2][0] = fmaf(a2, b.x, acc[2][0]); acc[2][1] = fmaf(a2, b.y, acc[2][1]);
            acc[2][2] = fmaf(a2, b.z, acc[2][2]); acc[2][3] = fmaf(a2, b.w, acc[2][3]);
            acc[3][0] = fmaf(a3, b.x, acc[3][0]); acc[3][1] = fmaf(a3, b.y, acc[3][1]);
            acc[3][2] = fmaf(a3, b.z, acc[3][2]); acc[3][3] = fmaf(a3, b.w, acc[3][3]);
        }
        #pragma unroll
        for (int i = 0; i < 4; ++i) {
            int r = row0 + ty * 4 + i;
            float dv = dinv[r];
            __half2 p0 = __floats2half2_rn(acc[i][0] * dv, acc[i][1] * dv);
            __half2 p1 = __floats2half2_rn(acc[i][2] * dv, acc[i][3] * dv);
            uint2 u;
            u.x = *(unsigned int*)&p0;
            u.y = *(unsigned int*)&p1;
            *(uint2*)&Y[(long)r * NFEAT + tx * 4] = u;
        }
    }
}

// ---------------- aggregation: out[v] = relu(dinv[v]*(tt[v] + sum_in tt[u]) + b) ----
// one wave per dst node, 2 f16 cols (half2 = 4B) per lane; f32 accumulate
__global__ __launch_bounds__(256) void k_agg(const unsigned int* __restrict__ TT,
    const int* __restrict__ rp, const int* __restrict__ csr,
    const float* __restrict__ dinv, const float* __restrict__ bias,
    unsigned int* __restrict__ OUT, int N)
{
    int wid = (blockIdx.x * 256 + threadIdx.x) >> 6;
    if (wid >= N) return;
    int lane = threadIdx.x & 63;
    long base = (long)wid * 64;
    unsigned int sv = TT[base + lane];
    float2 acc = __half22float2(*(const __half2*)&sv);   // self-loop term
    int e = rp[wid], e1 = rp[wid + 1];
    for (; e + 8 <= e1; e += 8) {
        int s0 = csr[e + 0], s1 = csr[e + 1], s2 = csr[e + 2], s3 = csr[e + 3];
        int s4 = csr[e + 4], s5 = csr[e + 5], s6 = csr[e + 6], s7 = csr[e + 7];
        unsigned int v0 = TT[(long)s0 * 64 + lane];
        unsigned int v1 = TT[(long)s1 * 64 + lane];
        unsigned int v2 = TT[(long)s2 * 64 + lane];
        unsigned int v3 = TT[(long)s3 * 64 + lane];
        unsigned int v4 = TT[(long)s4 * 64 + lane];
        unsigned int v5 = TT[(long)s5 * 64 + lane];
        unsigned int v6 = TT[(long)s6 * 64 + lane];
        unsigned int v7 = TT[(long)s7 * 64 + lane];
        float2 f0 = __half22float2(*(const __half2*)&v0);
        float2 f1 = __half22float2(*(const __half2*)&v1);
        float2 f2 = __half22float2(*(const __half2*)&v2);
        float2 f3 = __half22float2(*(const __half2*)&v3);
        float2 f4 = __half22float2(*(const __half2*)&v4);
        float2 f5 = __half22float2(*(const __half2*)&v5);
        float2 f6 = __half22float2(*(const __half2*)&v6);
        float2 f7 = __half22float2(*(const __half2*)&v7);
        acc.x += ((f0.x + f1.x) + (f2.x + f3.x)) + ((f4.x + f5.x) + (f6.x + f7.x));
        acc.y += ((f0.y + f1.y) + (f2.y + f3.y)) + ((f4.y + f5.y) + (f6.y + f7.y));
    }
    for (; e < e1; ++e) {
        int s = csr[e];
        unsigned int v = TT[(long)s * 64 + lane];
        float2 f = __half22float2(*(const __half2*)&v);
        acc.x += f.x; acc.y += f.y;
    }
    float dv = dinv[wid];
    float ox = fmaxf(fmaf(acc.x, dv, bias[lane * 2 + 0]), 0.f);
    float oy = fmaxf(fmaf(acc.y, dv, bias[lane * 2 + 1]), 0.f);
    __half2 o2 = __floats2half2_rn(ox, oy);
    OUT[base + lane] = *(unsigned int*)&o2;
}

// ---------------- fused head: relu(H@Wc1^T + bc1) @ Wc2^T + bc2  (H f16) ---------
__global__ __launch_bounds__(256) void k_head(const __half* __restrict__ H,
    const float* __restrict__ Wc1, const float* __restrict__ bc1,
    const float* __restrict__ Wc2, const float* __restrict__ bc2,
    float* __restrict__ OUT, int N)
{
    __shared__ float w1[16][132];
    __shared__ float hs[16][132];
    __shared__ float h16[16][17];
    for (int idx = threadIdx.x; idx < 16 * NFEAT; idx += 256) {
        int o = idx >> 7, k = idx & 127;
        w1[o][k] = Wc1[idx];
    }
    const unsigned int* Hu = (const unsigned int*)H;
    int ntiles = (N + 15) >> 4;
    for (int tile = blockIdx.x; tile < ntiles; tile += gridDim.x) {
        int row0 = tile << 4;
        __syncthreads();   // also covers w1 init on first iter
        #pragma unroll
        for (int it = 0; it < 4; ++it) {
            int idx = it * 256 + threadIdx.x;   // 0..1023
            int r = idx >> 6, p = idx & 63;
            int row = row0 + r;
            unsigned int v = (row < N) ? Hu[(long)row * 64 + p] : 0u;
            float2 f = __half22float2(*(const __half2*)&v);
            hs[r][p * 2] = f.x;
            hs[r][p * 2 + 1] = f.y;
        }
        __syncthreads();
        int r = threadIdx.x >> 4, o = threadIdx.x & 15;
        float acc = 0.f;
        #pragma unroll 8
        for (int k = 0; k < NFEAT; ++k) acc = fmaf(hs[r][k], w1[o][k], acc);
        h16[r][o] = fmaxf(acc + bc1[o], 0.f);
        __syncthreads();
        if (threadIdx.x < 32) {
            int rr = threadIdx.x >> 1, j = threadIdx.x & 1;
            float a = bc2[j];
            #pragma unroll
            for (int o2 = 0; o2 < 16; ++o2) a = fmaf(h16[rr][o2], Wc2[j * 16 + o2], a);
            int row = row0 + rr;
            if (row < N) OUT[(long)row * 2 + j] = a;
        }
        __syncthreads();
    }
}

extern "C" void kernel_launch(void* const* d_in, const int* in_sizes, int n_in,
                              void* d_out, int out_size, void* d_ws, size_t ws_size,
                              hipStream_t stream) {
    const float* x     = (const float*)d_in[0];
    const int*   ei    = (const int*)d_in[1];
    const float* gamma = (const float*)d_in[2];
    const float* beta  = (const float*)d_in[3];
    const float* W1    = (const float*)d_in[4];
    const float* b1    = (const float*)d_in[5];
    const float* W2    = (const float*)d_in[6];
    const float* b2    = (const float*)d_in[7];
    const float* Wc1   = (const float*)d_in[8];
    const float* bc1   = (const float*)d_in[9];
    const float* Wc2   = (const float*)d_in[10];
    const float* bc2   = (const float*)d_in[11];

    int N = in_sizes[0] / NFEAT;
    int E = in_sizes[1] / 2;
    const int* srcI = ei;
    const int* dstI = ei + E;
    int NB = (N + BSZ - 1) >> BSH;   // 196 for N=100k (<=256 required by k_bscan)

    char* ws = (char*)d_ws;
    size_t off = 0;
    auto alloc = [&](size_t bytes) {
        void* p = ws + off;
        off += bytes;
        off = (off + 511) & ~(size_t)511;
        return p;
    };
    __half* bufA  = (__half*)alloc((size_t)N * NFEAT * 2);   // h buffer
    __half* bufB  = (__half*)alloc((size_t)N * NFEAT * 2);   // tt buffer
    float* sum    = (float*)alloc(NFEAT * 4);
    float* sumsq  = (float*)alloc(NFEAT * 4);
    int*   deg    = (int*)alloc((size_t)N * 4);
    int*   rp     = (int*)alloc((size_t)(N + 1) * 4);
    float* dinv   = (float*)alloc((size_t)N * 4);
    int*   csr    = (int*)alloc((size_t)E * 4);
    int*   packed = (int*)alloc((size_t)E * 4);
    int*   bcnt   = (int*)alloc((size_t)(NB + 1) * 4);
    int*   boff   = (int*)alloc((size_t)(NB + 1) * 4);
    int*   bnxt   = (int*)alloc((size_t)(NB + 1) * 4);
    int*   part   = (int*)alloc(256 * 4);
    (void)ws_size;

    hipMemsetAsync(sum, 0, NFEAT * 4, stream);
    hipMemsetAsync(sumsq, 0, NFEAT * 4, stream);
    hipMemsetAsync(bcnt, 0, (size_t)(NB + 1) * 4, stream);

    long total = (long)N * NFEAT;
    int nb = (N + 1023) >> 10;          // scan blocks
    int nchunk = (E + 8191) >> 13;      // bucket partition blocks (8192 edges each)

    k_stats<<<1024, 256, 0, stream>>>(x, sum, sumsq, total);
    k_bn<<<2048, 256, 0, stream>>>(x, sum, sumsq, gamma, beta, bufA, total >> 2, 1.0f / (float)N);

    // graph build (bucketed counting sort, L2-window scatter)
    k_bhist<<<NB, 256, 0, stream>>>(dstI, bcnt, E, NB);
    k_bscan<<<1, 256, 0, stream>>>(bcnt, boff, bnxt, NB);
    k_bucket<<<nchunk, 256, 0, stream>>>(srcI, dstI, bnxt, packed, E, NB);
    k_bdeg<<<NB, 256, 0, stream>>>(packed, boff, deg, N);
    k_scan_a<<<nb, 256, 0, stream>>>(deg, part, N);
    k_scan_b<<<1, 256, 0, stream>>>(part, nb);
    k_scan_c<<<nb, 256, 0, stream>>>(deg, part, rp, dinv, N, E);
    k_place<<<NB, 256, 0, stream>>>(packed, boff, rp, csr, N);

    // layer 1
    k_gemm128<<<512, 256, 0, stream>>>(bufA, W1, dinv, bufB, N);
    k_agg<<<(N + 3) / 4, 256, 0, stream>>>((const unsigned int*)bufB, rp, csr, dinv, b1, (unsigned int*)bufA, N);
    // layer 2
    k_gemm128<<<512, 256, 0, stream>>>(bufA, W2, dinv, bufB, N);
    k_agg<<<(N + 3) / 4, 256, 0, stream>>>((const unsigned int*)bufB, rp, csr, dinv, b2, (unsigned int*)bufA, N);
    // head
    k_head<<<2048, 256, 0, stream>>>(bufA, Wc1, bc1, Wc2, bc2, (float*)d_out, N);
}

// Round 5
// 379.336 us; speedup vs baseline: 2.3500x; 1.1051x over previous
//
#include <hip/hip_runtime.h>
#include <hip/hip_fp16.h>

#define NFEAT 128
#define EPSV 1e-5f
#define BSH 9
#define BSZ 512   // nodes per dst-bucket

typedef _Float16 h8 __attribute__((ext_vector_type(8)));   // 8 halfs = 16B
typedef float f4 __attribute__((ext_vector_type(4)));

// ---------------- column stats (mean/var over N rows, 128 cols) ----------------
__global__ __launch_bounds__(256) void k_stats(const float* __restrict__ X,
    float* __restrict__ sum, float* __restrict__ sumsq, long total)
{
    float s = 0.f, q = 0.f;
    long stride = (long)gridDim.x * blockDim.x;
    for (long i = (long)blockIdx.x * blockDim.x + threadIdx.x; i < total; i += stride) {
        float v = X[i];
        s += v;
        q = fmaf(v, v, q);
    }
    __shared__ float ls[256], lq[256];
    ls[threadIdx.x] = s; lq[threadIdx.x] = q;
    __syncthreads();
    if (threadIdx.x < 128) {
        int c = threadIdx.x;            // stride is a multiple of 128 -> col == tid&127
        s = ls[c] + ls[c + 128];
        q = lq[c] + lq[c + 128];
        unsafeAtomicAdd(&sum[c], s);
        unsafeAtomicAdd(&sumsq[c], q);
    }
}

// ---------------- BN apply: xn = (x-mu)*rstd*gamma + beta  (write f16) ----------
__global__ __launch_bounds__(256) void k_bn(const float* __restrict__ X,
    const float* __restrict__ sum, const float* __restrict__ sumsq,
    const float* __restrict__ gamma, const float* __restrict__ beta,
    __half* __restrict__ XN, long total4, float invN)
{
    __shared__ float sc[NFEAT], sh[NFEAT];
    if (threadIdx.x < NFEAT) {
        int c = threadIdx.x;
        float mu = sum[c] * invN;
        float var = fmaf(-mu, mu, sumsq[c] * invN);
        float r = rsqrtf(var + EPSV);
        float g = r * gamma[c];
        sc[c] = g;
        sh[c] = fmaf(-mu, g, beta[c]);
    }
    __syncthreads();
    const float4* X4 = (const float4*)X;
    uint2* XN4 = (uint2*)XN;
    long stride = (long)gridDim.x * blockDim.x;
    for (long i = (long)blockIdx.x * blockDim.x + threadIdx.x; i < total4; i += stride) {
        int c0 = (int)((i << 2) & (NFEAT - 1));
        float4 v = X4[i];
        float4 o;
        o.x = fmaf(v.x, sc[c0 + 0], sh[c0 + 0]);
        o.y = fmaf(v.y, sc[c0 + 1], sh[c0 + 1]);
        o.z = fmaf(v.z, sc[c0 + 2], sh[c0 + 2]);
        o.w = fmaf(v.w, sc[c0 + 3], sh[c0 + 3]);
        __half2 h0 = __floats2half2_rn(o.x, o.y);
        __half2 h1 = __floats2half2_rn(o.z, o.w);
        uint2 u;
        u.x = *(unsigned int*)&h0;
        u.y = *(unsigned int*)&h1;
        XN4[i] = u;
    }
}

// ---------------- bucket histogram over dst>>BSH ----------------
__global__ __launch_bounds__(256) void k_bhist(const int* __restrict__ dst,
    int* __restrict__ bcnt, int E, int NB)
{
    __shared__ int hist[1024];
    for (int i = threadIdx.x; i < NB; i += 256) hist[i] = 0;
    __syncthreads();
    int stride = gridDim.x * 256;
    for (int e = blockIdx.x * 256 + threadIdx.x; e < E; e += stride)
        atomicAdd(&hist[dst[e] >> BSH], 1);
    __syncthreads();
    for (int i = threadIdx.x; i < NB; i += 256)
        if (hist[i]) atomicAdd(&bcnt[i], hist[i]);
}

// ---------------- scan bucket counts (NB <= 256) -> boff[NB+1], bnxt ----------------
__global__ __launch_bounds__(256) void k_bscan(const int* __restrict__ bcnt,
    int* __restrict__ boff, int* __restrict__ bnxt, int NB)
{
    __shared__ int ps[256];
    int t = threadIdx.x;
    int v = (t < NB) ? bcnt[t] : 0;
    ps[t] = v;
    __syncthreads();
    #pragma unroll
    for (int off = 1; off < 256; off <<= 1) {
        int u = ps[t];
        if (t >= off) u += ps[t - off];
        __syncthreads();
        ps[t] = u;
        __syncthreads();
    }
    if (t < NB) {
        int ex = ps[t] - v;
        boff[t] = ex;
        bnxt[t] = ex;
    }
    if (t == NB - 1) boff[NB] = ps[t];
}

// ---------------- partition edges into buckets, packed (src<<BSH | dst&511) ----------
__global__ __launch_bounds__(256) void k_bucket(const int* __restrict__ src,
    const int* __restrict__ dst, int* __restrict__ bnxt,
    int* __restrict__ packed, int E, int NB)
{
    __shared__ int hist[1024];
    __shared__ int base[1024];
    int c0 = blockIdx.x * 8192;
    int c1 = min(E, c0 + 8192);
    for (int i = threadIdx.x; i < NB; i += 256) hist[i] = 0;
    __syncthreads();
    for (int e = c0 + threadIdx.x; e < c1; e += 256)
        atomicAdd(&hist[dst[e] >> BSH], 1);
    __syncthreads();
    for (int i = threadIdx.x; i < NB; i += 256) {
        int h = hist[i];
        base[i] = h ? atomicAdd(&bnxt[i], h) : 0;
        hist[i] = 0;
    }
    __syncthreads();
    for (int e = c0 + threadIdx.x; e < c1; e += 256) {
        int d = dst[e];
        int b = d >> BSH;
        int p = base[b] + atomicAdd(&hist[b], 1);
        packed[p] = (src[e] << BSH) | (d & (BSZ - 1));
    }
}

// ---------------- per-bucket degree (LDS counters -> coalesced deg writes) --------
__global__ __launch_bounds__(256) void k_bdeg(const int* __restrict__ packed,
    const int* __restrict__ boff, int* __restrict__ deg, int N)
{
    __shared__ int cnt[BSZ];
    int b = blockIdx.x;
    for (int i = threadIdx.x; i < BSZ; i += 256) cnt[i] = 0;
    __syncthreads();
    int e0 = boff[b], e1 = boff[b + 1];
    for (int e = e0 + threadIdx.x; e < e1; e += 256)
        atomicAdd(&cnt[packed[e] & (BSZ - 1)], 1);
    __syncthreads();
    int nbase = b << BSH;
    for (int i = threadIdx.x; i < BSZ; i += 256)
        if (nbase + i < N) deg[nbase + i] = cnt[i];
}

// ---------------- 3-phase device-wide exclusive scan ----------------
__global__ __launch_bounds__(256) void k_scan_a(const int* __restrict__ deg,
    int* __restrict__ part, int N)
{
    int base = blockIdx.x << 10;
    int t = threadIdx.x;
    int s = 0;
    #pragma unroll
    for (int j = 0; j < 4; ++j) {
        int i = base + t * 4 + j;
        if (i < N) s += deg[i];
    }
    __shared__ int ls[256];
    ls[t] = s;
    __syncthreads();
    #pragma unroll
    for (int off = 128; off > 0; off >>= 1) {
        if (t < off) ls[t] += ls[t + off];
        __syncthreads();
    }
    if (t == 0) part[blockIdx.x] = ls[0];
}

__global__ __launch_bounds__(256) void k_scan_b(int* __restrict__ part, int nb)
{
    __shared__ int ps[256];
    int t = threadIdx.x;
    int v = (t < nb) ? part[t] : 0;
    ps[t] = v;
    __syncthreads();
    #pragma unroll
    for (int off = 1; off < 256; off <<= 1) {
        int u = ps[t];
        if (t >= off) u += ps[t - off];
        __syncthreads();
        ps[t] = u;
        __syncthreads();
    }
    if (t < nb) part[t] = ps[t] - v;   // exclusive
}

__global__ __launch_bounds__(256) void k_scan_c(const int* __restrict__ deg,
    const int* __restrict__ part, int* __restrict__ rp,
    float* __restrict__ dinv, int N, int E)
{
    int base = blockIdx.x << 10;
    int t = threadIdx.x;
    int v[4];
    int ts = 0;
    #pragma unroll
    for (int j = 0; j < 4; ++j) {
        int i = base + t * 4 + j;
        v[j] = (i < N) ? deg[i] : 0;
        ts += v[j];
    }
    __shared__ int ps[256];
    ps[t] = ts;
    __syncthreads();
    #pragma unroll
    for (int off = 1; off < 256; off <<= 1) {
        int u = ps[t];
        if (t >= off) u += ps[t - off];
        __syncthreads();
        ps[t] = u;
        __syncthreads();
    }
    int run = part[blockIdx.x] + ps[t] - ts;   // exclusive offset for this thread
    #pragma unroll
    for (int j = 0; j < 4; ++j) {
        int i = base + t * 4 + j;
        if (i < N) {
            rp[i] = run;
            dinv[i] = rsqrtf((float)(v[j] + 1));
            run += v[j];
        }
    }
    if (blockIdx.x == 0 && t == 0) rp[N] = E;
}

// ---------------- per-bucket CSR placement (writes confined to 33KB window) ------
__global__ __launch_bounds__(256) void k_place(const int* __restrict__ packed,
    const int* __restrict__ boff, const int* __restrict__ rp,
    int* __restrict__ csr, int N)
{
    __shared__ int nxt[BSZ];
    int b = blockIdx.x;
    int nbase = b << BSH;
    for (int i = threadIdx.x; i < BSZ; i += 256)
        nxt[i] = (nbase + i < N) ? rp[nbase + i] : 0;
    __syncthreads();
    int e0 = boff[b], e1 = boff[b + 1];
    for (int e = e0 + threadIdx.x; e < e1; e += 256) {
        int v = packed[e];
        int p = atomicAdd(&nxt[v & (BSZ - 1)], 1);
        csr[p] = v >> BSH;
    }
}

// ---------------- MFMA GEMM: Ys[s][n][16] = dinv[n] * (X[n]@W^T)[s*16..]  --------
// One wave per 16-row tile. W staged once/block to LDS f16 (stride 136 halfs ->
// bank-conflict-free b128 reads). A-frag: lane l = row(l&15), kgroup(l>>4), 16B
// contiguous global load. D-frag (measured): col=lane&15, row=(lane>>4)*4+reg.
// Output written in SLICED layout: slice s = n-tile, [s][node][16] f16 (3.2MB/slice).
__global__ __launch_bounds__(256) void k_gemm_mfma(const _Float16* __restrict__ X,
    const float* __restrict__ W, const float* __restrict__ dinv,
    _Float16* __restrict__ Ys, int N)
{
    __shared__ _Float16 w16[NFEAT * 136];   // [o][k], row stride 136
    for (int idx = threadIdx.x; idx < NFEAT * NFEAT; idx += 256) {
        int o = idx >> 7, k = idx & 127;
        w16[o * 136 + k] = (_Float16)W[idx];
    }
    __syncthreads();

    const h8* Xv = (const h8*)X;            // 16 h8-chunks per row
    const h8* Wv = (const h8*)w16;          // 17 h8-chunks per row
    int lane = threadIdx.x & 63;
    int lr = lane & 15;                      // row-in-tile / out-col
    int lk = lane >> 4;                      // k-subgroup (0..3)
    int wid = (blockIdx.x * blockDim.x + threadIdx.x) >> 6;
    int nw = (gridDim.x * blockDim.x) >> 6;
    int ntiles = N >> 4;

    for (int tile = wid; tile < ntiles; tile += nw) {
        int r0 = tile << 4;
        h8 a[4];
        #pragma unroll
        for (int kg = 0; kg < 4; ++kg)
            a[kg] = Xv[(long)(r0 + lr) * 16 + kg * 4 + lk];

        f4 acc[8];
        #pragma unroll
        for (int nt = 0; nt < 8; ++nt) acc[nt] = (f4)(0.f);

        #pragma unroll
        for (int nt = 0; nt < 8; ++nt) {
            int o = nt * 16 + lr;
            #pragma unroll
            for (int kg = 0; kg < 4; ++kg) {
                h8 b = Wv[o * 17 + kg * 4 + lk];
                acc[nt] = __builtin_amdgcn_mfma_f32_16x16x32_f16(a[kg], b, acc[nt], 0, 0, 0);
            }
        }

        int rbase = r0 + (lane >> 4) * 4;
        float dv0 = dinv[rbase + 0];
        float dv1 = dinv[rbase + 1];
        float dv2 = dinv[rbase + 2];
        float dv3 = dinv[rbase + 3];
        #pragma unroll
        for (int nt = 0; nt < 8; ++nt) {
            _Float16* dst = Ys + ((long)nt * N) * 16 + lr;
            dst[(long)(rbase + 0) * 16] = (_Float16)(acc[nt][0] * dv0);
            dst[(long)(rbase + 1) * 16] = (_Float16)(acc[nt][1] * dv1);
            dst[(long)(rbase + 2) * 16] = (_Float16)(acc[nt][2] * dv2);
            dst[(long)(rbase + 3) * 16] = (_Float16)(acc[nt][3] * dv3);
        }
    }
}

// ---------------- sliced aggregation: slice = blockIdx&7 -> pinned per XCD -------
// out[v][s*16..] = relu(dinv[v]*(tt_s[v] + sum_in tt_s[u]) + b[s*16..])
// 8 threads per node (32B contiguous gather per edge); slice table 3.2MB ~ L2.
__global__ __launch_bounds__(256) void k_agg(const unsigned int* __restrict__ TTs,
    const int* __restrict__ rp, const int* __restrict__ csr,
    const float* __restrict__ dinv, const float* __restrict__ bias,
    unsigned int* __restrict__ OUT, int N)
{
    int s = blockIdx.x & 7;
    int nb = blockIdx.x >> 3;
    int t = threadIdx.x;
    int node = nb * 32 + (t >> 3);
    if (node >= N) return;
    int sub = t & 7;
    const unsigned int* base = TTs + (long)s * N * 8;

    unsigned int sv = base[(long)node * 8 + sub];
    float2 acc = __half22float2(*(const __half2*)&sv);   // self-loop term
    int e = rp[node], e1 = rp[node + 1];
    for (; e + 4 <= e1; e += 4) {
        int s0 = csr[e + 0], s1 = csr[e + 1], s2 = csr[e + 2], s3 = csr[e + 3];
        unsigned int v0 = base[(long)s0 * 8 + sub];
        unsigned int v1 = base[(long)s1 * 8 + sub];
        unsigned int v2 = base[(long)s2 * 8 + sub];
        unsigned int v3 = base[(long)s3 * 8 + sub];
        float2 f0 = __half22float2(*(const __half2*)&v0);
        float2 f1 = __half22float2(*(const __half2*)&v1);
        float2 f2 = __half22float2(*(const __half2*)&v2);
        float2 f3 = __half22float2(*(const __half2*)&v3);
        acc.x += (f0.x + f1.x) + (f2.x + f3.x);
        acc.y += (f0.y + f1.y) + (f2.y + f3.y);
    }
    for (; e < e1; ++e) {
        unsigned int v = base[(long)csr[e] * 8 + sub];
        float2 f = __half22float2(*(const __half2*)&v);
        acc.x += f.x; acc.y += f.y;
    }
    float dv = dinv[node];
    float ox = fmaxf(fmaf(acc.x, dv, bias[s * 16 + sub * 2 + 0]), 0.f);
    float oy = fmaxf(fmaf(acc.y, dv, bias[s * 16 + sub * 2 + 1]), 0.f);
    __half2 o2 = __floats2half2_rn(ox, oy);
    OUT[(long)node * 64 + s * 8 + sub] = *(unsigned int*)&o2;   // row-major f16
}

// ---------------- fused head: relu(H@Wc1^T + bc1) @ Wc2^T + bc2  (H f16) ---------
__global__ __launch_bounds__(256) void k_head(const __half* __restrict__ H,
    const float* __restrict__ Wc1, const float* __restrict__ bc1,
    const float* __restrict__ Wc2, const float* __restrict__ bc2,
    float* __restrict__ OUT, int N)
{
    __shared__ float w1[16][132];
    __shared__ float hs[16][132];
    __shared__ float h16[16][17];
    for (int idx = threadIdx.x; idx < 16 * NFEAT; idx += 256) {
        int o = idx >> 7, k = idx & 127;
        w1[o][k] = Wc1[idx];
    }
    const unsigned int* Hu = (const unsigned int*)H;
    int ntiles = (N + 15) >> 4;
    for (int tile = blockIdx.x; tile < ntiles; tile += gridDim.x) {
        int row0 = tile << 4;
        __syncthreads();   // also covers w1 init on first iter
        #pragma unroll
        for (int it = 0; it < 4; ++it) {
            int idx = it * 256 + threadIdx.x;   // 0..1023
            int r = idx >> 6, p = idx & 63;
            int row = row0 + r;
            unsigned int v = (row < N) ? Hu[(long)row * 64 + p] : 0u;
            float2 f = __half22float2(*(const __half2*)&v);
            hs[r][p * 2] = f.x;
            hs[r][p * 2 + 1] = f.y;
        }
        __syncthreads();
        int r = threadIdx.x >> 4, o = threadIdx.x & 15;
        float acc = 0.f;
        #pragma unroll 8
        for (int k = 0; k < NFEAT; ++k) acc = fmaf(hs[r][k], w1[o][k], acc);
        h16[r][o] = fmaxf(acc + bc1[o], 0.f);
        __syncthreads();
        if (threadIdx.x < 32) {
            int rr = threadIdx.x >> 1, j = threadIdx.x & 1;
            float a = bc2[j];
            #pragma unroll
            for (int o2 = 0; o2 < 16; ++o2) a = fmaf(h16[rr][o2], Wc2[j * 16 + o2], a);
            int row = row0 + rr;
            if (row < N) OUT[(long)row * 2 + j] = a;
        }
        __syncthreads();
    }
}

extern "C" void kernel_launch(void* const* d_in, const int* in_sizes, int n_in,
                              void* d_out, int out_size, void* d_ws, size_t ws_size,
                              hipStream_t stream) {
    const float* x     = (const float*)d_in[0];
    const int*   ei    = (const int*)d_in[1];
    const float* gamma = (const float*)d_in[2];
    const float* beta  = (const float*)d_in[3];
    const float* W1    = (const float*)d_in[4];
    const float* b1    = (const float*)d_in[5];
    const float* W2    = (const float*)d_in[6];
    const float* b2    = (const float*)d_in[7];
    const float* Wc1   = (const float*)d_in[8];
    const float* bc1   = (const float*)d_in[9];
    const float* Wc2   = (const float*)d_in[10];
    const float* bc2   = (const float*)d_in[11];

    int N = in_sizes[0] / NFEAT;
    int E = in_sizes[1] / 2;
    const int* srcI = ei;
    const int* dstI = ei + E;
    int NB = (N + BSZ - 1) >> BSH;   // 196 for N=100k (<=256 required by k_bscan)

    char* ws = (char*)d_ws;
    size_t off = 0;
    auto alloc = [&](size_t bytes) {
        void* p = ws + off;
        off += bytes;
        off = (off + 511) & ~(size_t)511;
        return p;
    };
    __half* bufA  = (__half*)alloc((size_t)N * NFEAT * 2);   // h buffer (row-major)
    __half* bufB  = (__half*)alloc((size_t)N * NFEAT * 2);   // tt buffer (sliced)
    float* sum    = (float*)alloc(NFEAT * 4);
    float* sumsq  = (float*)alloc(NFEAT * 4);
    int*   deg    = (int*)alloc((size_t)N * 4);
    int*   rp     = (int*)alloc((size_t)(N + 1) * 4);
    float* dinv   = (float*)alloc((size_t)N * 4);
    int*   csr    = (int*)alloc((size_t)E * 4);
    int*   packed = (int*)alloc((size_t)E * 4);
    int*   bcnt   = (int*)alloc((size_t)(NB + 1) * 4);
    int*   boff   = (int*)alloc((size_t)(NB + 1) * 4);
    int*   bnxt   = (int*)alloc((size_t)(NB + 1) * 4);
    int*   part   = (int*)alloc(256 * 4);
    (void)ws_size;

    hipMemsetAsync(sum, 0, NFEAT * 4, stream);
    hipMemsetAsync(sumsq, 0, NFEAT * 4, stream);
    hipMemsetAsync(bcnt, 0, (size_t)(NB + 1) * 4, stream);

    long total = (long)N * NFEAT;
    int nb = (N + 1023) >> 10;          // scan blocks
    int nchunk = (E + 8191) >> 13;      // bucket partition blocks (8192 edges each)
    int naggb = ((N + 31) / 32) * 8;    // agg: node-blocks x 8 slices

    k_stats<<<1024, 256, 0, stream>>>(x, sum, sumsq, total);
    k_bn<<<2048, 256, 0, stream>>>(x, sum, sumsq, gamma, beta, bufA, total >> 2, 1.0f / (float)N);

    // graph build (bucketed counting sort, L2-window scatter)
    k_bhist<<<NB, 256, 0, stream>>>(dstI, bcnt, E, NB);
    k_bscan<<<1, 256, 0, stream>>>(bcnt, boff, bnxt, NB);
    k_bucket<<<nchunk, 256, 0, stream>>>(srcI, dstI, bnxt, packed, E, NB);
    k_bdeg<<<NB, 256, 0, stream>>>(packed, boff, deg, N);
    k_scan_a<<<nb, 256, 0, stream>>>(deg, part, N);
    k_scan_b<<<1, 256, 0, stream>>>(part, nb);
    k_scan_c<<<nb, 256, 0, stream>>>(deg, part, rp, dinv, N, E);
    k_place<<<NB, 256, 0, stream>>>(packed, boff, rp, csr, N);

    // layer 1
    k_gemm_mfma<<<512, 256, 0, stream>>>((const _Float16*)bufA, W1, dinv, (_Float16*)bufB, N);
    k_agg<<<naggb, 256, 0, stream>>>((const unsigned int*)bufB, rp, csr, dinv, b1, (unsigned int*)bufA, N);
    // layer 2
    k_gemm_mfma<<<512, 256, 0, stream>>>((const _Float16*)bufA, W2, dinv, (_Float16*)bufB, N);
    k_agg<<<naggb, 256, 0, stream>>>((const unsigned int*)bufB, rp, csr, dinv, b2, (unsigned int*)bufA, N);
    // head
    k_head<<<2048, 256, 0, stream>>>(bufA, Wc1, bc1, Wc2, bc2, (float*)d_out, N);
}